// Round 4
// baseline (3757.109 us; speedup 1.0000x reference)
//
#include <hip/hip_runtime.h>

#define Bdim 64
#define Ndim 512
#define Hdim 2048
#define KSPLIT 8
#define NCHUNK 8
#define LNEPS 1e-5f

typedef unsigned short u16;

__device__ __forceinline__ u16 f2bf(float f) {
    unsigned int u = __float_as_uint(f);
    return (u16)((u + 0x7FFFu + ((u >> 16) & 1u)) >> 16);
}
__device__ __forceinline__ float bf2f(u16 s) {
    return __uint_as_float(((unsigned int)s) << 16);
}

// Partials-only GEMV: part[ks][b][o] = sum_{k in ks-range} Xeff[b,k]*Weff[o,k]
// WMODE 0: Weff[o,k] = W[o*H+k]  (Y = X @ W^T)
// WMODE 1: Weff[o,k] = W[k*H+o]  (Y = X @ W)
// XPART 1: Xeff[b,k] = sum_s Xp[s][b][k] (+ xbias[k])  -- consumer-side combine
// No cross-block sync, no fences: coherence via kernel boundaries only.
template<int WMODE, int XPART, int XBIAS>
__global__ __launch_bounds__(256)
void gemv_p(const float* __restrict__ X, const float* __restrict__ W,
            const float* __restrict__ xbias, float* __restrict__ part)
{
    __shared__ float Xs[64][68];     // pad 68: reads are 4-addr broadcast
    __shared__ float Ws[64][64];     // XOR col-quad swizzle
    const int t  = threadIdx.x;
    const int oc = blockIdx.x & 31;
    const int ks = blockIdx.x >> 5;
    const int o0 = oc * 64;
    const int k0 = ks * 256;
    const int bg = t >> 4;      // 0..15
    const int og = t & 15;      // 0..15

    float4 xr[4], wr[4];
    auto loadc = [&](int kb) {
        float4 bv;
        if (XPART && XBIAS) bv = *(const float4*)(xbias + kb + og * 4);
#pragma unroll
        for (int i = 0; i < 4; ++i) {
            const int r = i * 16 + bg;
            if (!XPART) {
                xr[i] = *(const float4*)(X + (size_t)r * Hdim + kb + og * 4);
            } else {
                float4 s;
                if (XBIAS) s = bv; else s = make_float4(0.f, 0.f, 0.f, 0.f);
#pragma unroll
                for (int ss = 0; ss < KSPLIT; ++ss) {
                    float4 p = *(const float4*)(X + (size_t)(ss * 64 + r) * Hdim + kb + og * 4);
                    s.x += p.x; s.y += p.y; s.z += p.z; s.w += p.w;
                }
                xr[i] = s;
            }
            if (WMODE == 0)
                wr[i] = *(const float4*)(W + (size_t)(o0 + r) * Hdim + kb + og * 4);
            else
                wr[i] = *(const float4*)(W + (size_t)(kb + r) * Hdim + o0 + og * 4);
        }
    };
    auto storec = [&]() {
#pragma unroll
        for (int i = 0; i < 4; ++i) {
            const int r = i * 16 + bg;
            *(float4*)(&Xs[r][og * 4]) = xr[i];
            if (WMODE == 0) {
                *(float4*)(&Ws[r][(og ^ ((r >> 2) & 7)) << 2]) = wr[i];
            } else {
                // wr[i] holds W[kb+r][o0+og*4 .. +3] -> scatter-transpose
                const int col = ((((r >> 2) ^ (og & 7)) << 2) | (r & 3));
                Ws[og * 4 + 0][col] = wr[i].x;
                Ws[og * 4 + 1][col] = wr[i].y;
                Ws[og * 4 + 2][col] = wr[i].z;
                Ws[og * 4 + 3][col] = wr[i].w;
            }
        }
    };

    float acc[4][4];
#pragma unroll
    for (int j = 0; j < 4; ++j)
#pragma unroll
        for (int oi = 0; oi < 4; ++oi) acc[j][oi] = 0.f;

    loadc(k0);
#pragma unroll
    for (int c = 0; c < 4; ++c) {
        __syncthreads();
        storec();
        __syncthreads();
        if (c < 3) loadc(k0 + (c + 1) * 64);   // prefetch overlaps compute
#pragma unroll
        for (int kkq = 0; kkq < 16; ++kkq) {
            float4 xj[4];
#pragma unroll
            for (int j = 0; j < 4; ++j)
                xj[j] = *(const float4*)(&Xs[bg * 4 + j][kkq * 4]);
#pragma unroll
            for (int oi = 0; oi < 4; ++oi) {
                float4 w = *(const float4*)(&Ws[og * 4 + oi][(kkq ^ (og & 7)) << 2]);
#pragma unroll
                for (int j = 0; j < 4; ++j) {
                    acc[j][oi] += xj[j].x * w.x + xj[j].y * w.y
                                + xj[j].z * w.z + xj[j].w * w.w;
                }
            }
        }
    }
#pragma unroll
    for (int j = 0; j < 4; ++j) {
        const int b = bg * 4 + j;
        float4 v = make_float4(acc[j][0], acc[j][1], acc[j][2], acc[j][3]);
        *(float4*)(part + (size_t)(ks * 64 + b) * Hdim + o0 + og * 4) = v;
    }
}

// Y[b,o] (=|+=) sum_s part[s][b][o] + bias[o]; optionally also write out.
template<int ACC, int FINAL>
__global__ __launch_bounds__(256)
void combine(const float* __restrict__ part, const float* __restrict__ bias,
             float* __restrict__ Y, float* __restrict__ out, int has_loss)
{
    const int flat4 = blockIdx.x * 256 + threadIdx.x;   // 0..32767
    const size_t e  = (size_t)flat4 * 4;
    const int o     = (int)(e & (Hdim - 1));
    float4 v = *(const float4*)(bias + o);
#pragma unroll
    for (int s = 0; s < KSPLIT; ++s) {
        float4 p = *(const float4*)(part + (size_t)s * (64 * Hdim) + e);
        v.x += p.x; v.y += p.y; v.z += p.z; v.w += p.w;
    }
    if (ACC) {
        float4 a = *(const float4*)(Y + e);
        v.x += a.x; v.y += a.y; v.z += a.z; v.w += a.w;
    }
    *(float4*)(Y + e) = v;
    if (FINAL) {
        *(float4*)(out + e) = v;
        if (has_loss && flat4 == 0) out[Bdim * Hdim] = 0.f;
    }
}

// One (b, 8-row n-chunk): theta_l from partials, scores -> local softmax ->
// partial weighted lfb sum (bf16 out). FIRST: read f32 lfb, also write bf16
// cache; else read bf16 cache (L3-resident).
template<int FIRST>
__global__ __launch_bounds__(256)
void flash_chunk(const float* __restrict__ lfb, const u16* __restrict__ lfb16,
                 u16* __restrict__ lfb16w, const float* __restrict__ thpart,
                 float scale, u16* __restrict__ up,
                 float* __restrict__ wm, float* __restrict__ wz)
{
    __shared__ u16 T[NCHUNK][Hdim];   // 32 KB
    __shared__ float th[Hdim];        // 8 KB
    __shared__ float sc[NCHUNK];
    __shared__ float wts[NCHUNK];
    const int t  = threadIdx.x;
    const int b  = blockIdx.x >> 6;
    const int ch = blockIdx.x & 63;
    const size_t nbase = (size_t)b * Ndim + ch * NCHUNK;
#pragma unroll
    for (int i = 0; i < 16; ++i) {
        int flat4 = i * 256 + t;
        int row   = flat4 >> 9;
        int c4    = flat4 & 511;
        if (FIRST) {
            float4 v = *(const float4*)(lfb + (nbase + row) * Hdim + c4 * 4);
            ushort4 u4;
            u4.x = f2bf(v.x); u4.y = f2bf(v.y); u4.z = f2bf(v.z); u4.w = f2bf(v.w);
            *(ushort4*)(&T[row][c4 * 4]) = u4;
            *(ushort4*)(lfb16w + (nbase + row) * Hdim + c4 * 4) = u4;
        } else {
            ushort4 u4 = *(const ushort4*)(lfb16 + (nbase + row) * Hdim + c4 * 4);
            *(ushort4*)(&T[row][c4 * 4]) = u4;
        }
    }
#pragma unroll
    for (int i = 0; i < 2; ++i) {
        int c = (i * 256 + t) * 4;
        float4 v = make_float4(0.f, 0.f, 0.f, 0.f);
#pragma unroll
        for (int s = 0; s < KSPLIT; ++s) {
            float4 p = *(const float4*)(thpart + (size_t)(s * 64 + b) * Hdim + c);
            v.x += p.x; v.y += p.y; v.z += p.z; v.w += p.w;
        }
        *(float4*)(&th[c]) = v;
    }
    __syncthreads();
    const int wv = t >> 6, ln = t & 63;
#pragma unroll
    for (int q = 0; q < 2; ++q) {
        int n = wv * 2 + q;
        float a = 0.f;
#pragma unroll
        for (int i = 0; i < 8; ++i) {
            int c = ln * 4 + i * 256;
            ushort4 x = *(const ushort4*)(&T[n][c]);
            float4 y  = *(const float4*)(&th[c]);
            a += bf2f(x.x) * y.x + bf2f(x.y) * y.y + bf2f(x.z) * y.z + bf2f(x.w) * y.w;
        }
#pragma unroll
        for (int off = 32; off; off >>= 1) a += __shfl_xor(a, off, 64);
        if (ln == 0) sc[n] = a * scale;
    }
    __syncthreads();
    float m = sc[0];
#pragma unroll
    for (int n = 1; n < NCHUNK; ++n) m = fmaxf(m, sc[n]);
    if (t < NCHUNK) wts[t] = expf(sc[t] - m);
    __syncthreads();
    if (t == 0) {
        float z = 0.f;
#pragma unroll
        for (int n = 0; n < NCHUNK; ++n) z += wts[n];
        wm[blockIdx.x] = m;
        wz[blockIdx.x] = z;
    }
#pragma unroll
    for (int i = 0; i < 8; ++i) {
        int c = t + i * 256;
        float a = 0.f;
#pragma unroll
        for (int n = 0; n < NCHUNK; ++n) a += wts[n] * bf2f(T[n][c]);
        up[(size_t)blockIdx.x * Hdim + c] = f2bf(a);
    }
}

__global__ __launch_bounds__(256)
void flash_comb(const u16* __restrict__ up, const float* __restrict__ wm,
                const float* __restrict__ wz, float* __restrict__ u)
{
    __shared__ float mm[64], zz[64], ee[64];
    const int t  = threadIdx.x;
    const int b  = blockIdx.x >> 3;
    const int sl = blockIdx.x & 7;
    if (t < 64) { mm[t] = wm[b * 64 + t]; zz[t] = wz[b * 64 + t]; }
    __syncthreads();
    float mg = mm[0];
#pragma unroll
    for (int i = 1; i < 64; ++i) mg = fmaxf(mg, mm[i]);
    if (t < 64) ee[t] = expf(mm[t] - mg);
    __syncthreads();
    float Z = 0.f;
#pragma unroll
    for (int i = 0; i < 64; ++i) Z += zz[i] * ee[i];
    const float inv = 1.f / Z;
    const int col = sl * 256 + t;
    float a = 0.f;
#pragma unroll 8
    for (int ch = 0; ch < 64; ++ch)
        a += ee[ch] * bf2f(up[(size_t)(b * 64 + ch) * Hdim + col]);
    u[(size_t)b * Hdim + col] = a * inv;
}

// r = relu(layernorm(sum_s part[s][b][:] + bias))
__global__ __launch_bounds__(256)
void ln_relu_part(const float* __restrict__ part, const float* __restrict__ bias,
                  float* __restrict__ r)
{
    __shared__ float trow[Hdim];
    __shared__ float red[8];
    const int t = threadIdx.x, b = blockIdx.x;
    float sum = 0.f, sq = 0.f;
#pragma unroll
    for (int i = 0; i < 2; ++i) {
        int c = (i * 256 + t) * 4;
        float4 v = *(const float4*)(bias + c);
#pragma unroll
        for (int s = 0; s < KSPLIT; ++s) {
            float4 p = *(const float4*)(part + ((size_t)(s * 64 + b)) * Hdim + c);
            v.x += p.x; v.y += p.y; v.z += p.z; v.w += p.w;
        }
        *(float4*)(&trow[c]) = v;
        sum += v.x + v.y + v.z + v.w;
        sq  += v.x * v.x + v.y * v.y + v.z * v.z + v.w * v.w;
    }
#pragma unroll
    for (int off = 32; off; off >>= 1) {
        sum += __shfl_xor(sum, off, 64);
        sq  += __shfl_xor(sq,  off, 64);
    }
    if ((t & 63) == 0) { red[t >> 6] = sum; red[4 + (t >> 6)] = sq; }
    __syncthreads();
    sum = red[0] + red[1] + red[2] + red[3];
    sq  = red[4] + red[5] + red[6] + red[7];
    const float mu   = sum * (1.f / Hdim);
    const float var  = sq * (1.f / Hdim) - mu * mu;
    const float rstd = rsqrtf(var + LNEPS);
#pragma unroll
    for (int i = 0; i < 2; ++i) {
        int c = (i * 256 + t) * 4;
        float4 v = *(const float4*)(&trow[c]);
        float4 o;
        o.x = fmaxf(0.f, (v.x - mu) * rstd);
        o.y = fmaxf(0.f, (v.y - mu) * rstd);
        o.z = fmaxf(0.f, (v.z - mu) * rstd);
        o.w = fmaxf(0.f, (v.w - mu) * rstd);
        *(float4*)(r + (size_t)b * Hdim + c) = o;
    }
}

extern "C" void kernel_launch(void* const* d_in, const int* in_sizes, int n_in,
                              void* d_out, int out_size, void* d_ws, size_t ws_size,
                              hipStream_t stream) {
    (void)in_sizes; (void)n_in; (void)ws_size;
    const float* clip = (const float*)d_in[0];
    const float* lfb  = (const float*)d_in[1];
    const float* Wc   = (const float*)d_in[2];
    const float* bc   = (const float*)d_in[3];
    const float* Wl   = (const float*)d_in[4];
    const float* bl   = (const float*)d_in[5];
    const float* Wt   = (const float*)d_in[6];
    const float* bt   = (const float*)d_in[7];
    const float* Wp   = (const float*)d_in[8];
    // d_in[9] = bp: cancels in softmax (per-row constant) -> unused
    const float* Wg   = (const float*)d_in[10];
    const float* bg   = (const float*)d_in[11];
    const float* Wo   = (const float*)d_in[12];
    const float* bo   = (const float*)d_in[13];
    float* out = (float*)d_out;

    // Workspace (float offsets); u16 buffers counted in f32 slots.
    float* wsf  = (float*)d_ws;
    float* A    = wsf;                        // 131072
    float* u    = wsf + 131072;
    float* r    = wsf + 262144;
    float* PA   = wsf + 393216;               // 8*64*2048 = 1048576
    float* PB   = wsf + 1441792;              // 1048576
    float* wm   = wsf + 2490368;              // 4096
    float* wz   = wsf + 2494464;              // 4096
    u16*   up    = (u16*)(wsf + 2498560);     // 4096*2048 u16 = 4,194,304 f32 slots
    u16*   lfb16 = (u16*)(wsf + 2498560 + 4194304);  // 64*512*2048 u16 = 33,554,432 f32 slots
    // total 40,247,296 floats = 161 MB

    const float scale = 0.022097086912079608f;   // 1/sqrt(2048)
    dim3 blk(256);
    const int has_loss = (out_size > Bdim * Hdim) ? 1 : 0;

    // A = clip @ Wc^T + bc
    gemv_p<0,0,0><<<256, blk, 0, stream>>>(clip, Wc, nullptr, PA);
    combine<0,0><<<128, blk, 0, stream>>>(PA, bc, A, nullptr, 0);

    for (int l = 0; l < 3; ++l) {
        // theta partials = A @ Wt^T   (bt added by consumer)
        gemv_p<0,0,0><<<256, blk, 0, stream>>>(A, Wt, nullptr, PA);
        // thetap partials = (sum PA + bt) @ Wp
        gemv_p<1,1,1><<<256, blk, 0, stream>>>(PA, Wp, bt, PB);
        // thetal partials = (sum PB) @ Wl
        gemv_p<1,1,0><<<256, blk, 0, stream>>>(PB, Wl, nullptr, PA);
        // fused scores/softmax/weighted-sum (sums PA for theta_l)
        if (l == 0)
            flash_chunk<1><<<4096, blk, 0, stream>>>(lfb, nullptr, lfb16, PA, scale, up, wm, wz);
        else
            flash_chunk<0><<<4096, blk, 0, stream>>>(nullptr, lfb16, nullptr, PA, scale, up, wm, wz);
        flash_comb<<<512, blk, 0, stream>>>(up, wm, wz, u);
        // s partials = u @ Wl^T   (bl added by consumer)
        gemv_p<0,0,0><<<256, blk, 0, stream>>>(u, Wl, nullptr, PB);
        // t partials = (sum PB + bl) @ Wg^T   (bg added in LN)
        gemv_p<0,1,1><<<256, blk, 0, stream>>>(PB, Wg, bl, PA);
        // r = relu(LN(sum PA + bg))
        ln_relu_part<<<64, blk, 0, stream>>>(PA, bg, r);
        // o partials = r @ Wo^T; A += sum + bo  (last layer also writes out)
        gemv_p<0,0,0><<<256, blk, 0, stream>>>(r, Wo, nullptr, PB);
        if (l < 2)
            combine<1,0><<<128, blk, 0, stream>>>(PB, bo, A, nullptr, 0);
        else
            combine<1,1><<<128, blk, 0, stream>>>(PB, bo, A, out, has_loss);
    }
}